// Round 5
// baseline (367.438 us; speedup 1.0000x reference)
//
#include <hip/hip_runtime.h>

// DigitCaps routing via MFMA, u_hat never materialized.
// B=512, R=1152, J=10, O=16, I=8, JO=160, K=R*I=9216.
// s[b,jo]    = sum_k x[b,k] * Wc[k,jo],  Wc[(r,i),(j,o)] = W[r,j,o,i]*c[r,j]
// v          = s*|s|/(1+s^2)
// bias[r,j] += (1/B) sum_{i,o} W[r,j,o,i] * M[(r,i),(j,o)],  M = x_r^T @ v
// c          = softmax_r(bias)
//
// r4 lesson: the k-split part buffer (sgemm -> global -> squash) cost ~28us/iter
// structurally. fwd_kernel now does GEMM + k-slice reduce (via LDS, fixed order)
// + squash + vfrag emit in ONE kernel: 16 blocks x 8 waves (2 m16 x 4 k-slices),
// no global intermediate. Iter 0 uses unscaled Wf and folds c=1/R into the
// f32 epilogue.

#define B_   512
#define R_   1152
#define JO_  160
#define K_   9216

typedef __attribute__((ext_vector_type(4))) float f32x4;
typedef __attribute__((ext_vector_type(8))) short bf16x8;

__device__ __forceinline__ short f2bf(float f) {
  unsigned int u = __float_as_uint(f);
  unsigned int r = (u + 0x7FFFu + ((u >> 16) & 1u)) >> 16;
  return (short)r;
}

__global__ __launch_bounds__(256) void init_kernel(float* __restrict__ bias) {
  int idx = blockIdx.x * 256 + threadIdx.x;
  if (idx < R_ * 10) bias[idx] = 0.0f;
}

// ---- one-time: x -> A-fragment order for the s-GEMM.
// frag f = m16*288+ks; lane l: row m16*16+(l&15), k = ks*32+(l>>4)*8+t.
__global__ __launch_bounds__(256) void xafbuild_kernel(
    const float* __restrict__ x, short* __restrict__ xaf) {
  int gid = blockIdx.x * 256 + threadIdx.x;  // < 589824
  int lane = gid & 63, f = gid >> 6;
  int ks = f % 288, m16 = f / 288;
  int row = m16 * 16 + (lane & 15);
  int k0 = ks * 32 + (lane >> 4) * 8;
  const float4* p = (const float4*)(x + (size_t)row * K_ + k0);
  float4 a = p[0], b = p[1];
  bf16x8 pk;
  pk[0] = f2bf(a.x); pk[1] = f2bf(a.y); pk[2] = f2bf(a.z); pk[3] = f2bf(a.w);
  pk[4] = f2bf(b.x); pk[5] = f2bf(b.y); pk[6] = f2bf(b.z); pk[7] = f2bf(b.w);
  ((bf16x8*)xaf)[gid] = pk;
}

// ---- one-time: x^T -> A-fragment order for agreement.
// frag f = rp*16+kb; lane l: row (l&15) of r-pair rp, k = b = kb*32+(l>>4)*8+t.
__global__ __launch_bounds__(256) void xtfbuild_kernel(
    const float* __restrict__ x, short* __restrict__ xtf) {
  int gid = blockIdx.x * 256 + threadIdx.x;  // < 589824
  int lane = gid & 63, f = gid >> 6;
  int kb = f & 15, rp = f >> 4;
  int b0 = kb * 32 + (lane >> 4) * 8;
  const float* p = x + (size_t)b0 * K_ + rp * 16 + (lane & 15);
  bf16x8 pk;
#pragma unroll
  for (int t = 0; t < 8; ++t) pk[t] = f2bf(p[(size_t)t * K_]);
  ((bf16x8*)xtf)[gid] = pk;
}

// Build Wc (or unscaled Wf when c==null) in B-fragment order.
// frag (kb*10+nb), lane l: k=kb*32+(l>>4)*8+t, n=nb*16+(l&15). grid 720.
__global__ __launch_bounds__(256) void wcbuild_kernel(
    const float* __restrict__ W, const float* __restrict__ c,
    short* __restrict__ wcf) {
  int idx = blockIdx.x * 256 + threadIdx.x;  // < 184320
  int lane = idx & 63;
  int rest = idx >> 6;
  int nb = rest % 10, kb = rest / 10;
  int k0 = kb * 32 + (lane >> 4) * 8;
  int r = k0 >> 3;
  int j = nb, o = lane & 15;
  const float4* wp = (const float4*)(W + (((size_t)r * 10 + j) * 16 + o) * 8);
  float4 a = wp[0], b = wp[1];
  float cs = c ? c[r * 10 + j] : 1.0f;
  bf16x8 pk;
  pk[0] = f2bf(a.x * cs); pk[1] = f2bf(a.y * cs);
  pk[2] = f2bf(a.z * cs); pk[3] = f2bf(a.w * cs);
  pk[4] = f2bf(b.x * cs); pk[5] = f2bf(b.y * cs);
  pk[6] = f2bf(b.z * cs); pk[7] = f2bf(b.w * cs);
  ((bf16x8*)wcf)[idx] = pk;
}

// Fused s-GEMM + k-reduce + squash + v-fragment emit.
// grid 16 (32 batch rows each), 512 threads = 8 waves: w = kw*2+mw,
// mw: which 16-row tile, kw: k-slice (72 of 288 k-steps).
// Partials cross waves via LDS (fixed-order 4-way sum -> deterministic).
template <bool SCALE>
__global__ __launch_bounds__(512) void fwd_kernel(
    const float* __restrict__ x, const short* __restrict__ xaf,
    const short* __restrict__ wcf, short* __restrict__ vfrag,
    float* __restrict__ out) {
  __shared__ float sm[20992];  // [8 waves][64 lanes][41]; aliased as [32][162]
  const int tid = threadIdx.x;
  const int w = tid >> 6, lane = tid & 63;
  const int mw = w & 1, kw = w >> 1;
  const int bb = blockIdx.x;  // batch rows bb*32 .. +32
  const int m16 = bb * 2 + mw;

  f32x4 acc[10] = {};
  const bf16x8* bp = (const bf16x8*)wcf + ((size_t)(kw * 72) * 640 + lane);
  if (xaf) {
    const bf16x8* ap =
        (const bf16x8*)xaf + ((size_t)m16 * 288 + kw * 72) * 64 + lane;
    for (int st = 0; st < 72; ++st) {
      bf16x8 af = ap[0];
      ap += 64;
#pragma unroll
      for (int nb = 0; nb < 10; ++nb)
        acc[nb] = __builtin_amdgcn_mfma_f32_16x16x32_bf16(af, bp[nb * 64],
                                                          acc[nb], 0, 0, 0);
      bp += 640;
    }
  } else {
    const int row = bb * 32 + mw * 16 + (lane & 15);
    const float* xrow = x + (size_t)row * K_ + (lane >> 4) * 8;
    for (int st = 0; st < 72; ++st) {
      const float4* apf = (const float4*)(xrow + (kw * 72 + st) * 32);
      float4 a0 = apf[0], a1 = apf[1];
      bf16x8 af;
      af[0] = f2bf(a0.x); af[1] = f2bf(a0.y);
      af[2] = f2bf(a0.z); af[3] = f2bf(a0.w);
      af[4] = f2bf(a1.x); af[5] = f2bf(a1.y);
      af[6] = f2bf(a1.z); af[7] = f2bf(a1.w);
#pragma unroll
      for (int nb = 0; nb < 10; ++nb)
        acc[nb] = __builtin_amdgcn_mfma_f32_16x16x32_bf16(af, bp[nb * 64],
                                                          acc[nb], 0, 0, 0);
      bp += 640;
    }
  }
  // stage per-wave partials: lane-local 40 floats, stride 41 (2-way max alias)
  {
    float* dst = sm + (size_t)(w * 64 + lane) * 41;
#pragma unroll
    for (int nb = 0; nb < 10; ++nb)
#pragma unroll
      for (int q = 0; q < 4; ++q) dst[nb * 4 + q] = acc[nb][q];
  }
  __syncthreads();
  // reduce 4 k-slices (fixed order) + squash; 10 values/thread
  float vals[10];
  const int e0 = tid * 10;
  const int mwr = e0 / 2560;
  const int rem = e0 - mwr * 2560;
  const int lr = rem / 40, c0 = rem - lr * 40;
#pragma unroll
  for (int u = 0; u < 10; ++u) {
    int cc = c0 + u;
    float s = sm[((0 + mwr) * 64 + lr) * 41 + cc] +
              sm[((2 + mwr) * 64 + lr) * 41 + cc] +
              sm[((4 + mwr) * 64 + lr) * 41 + cc] +
              sm[((6 + mwr) * 64 + lr) * 41 + cc];
    if (SCALE) s *= (1.0f / 1152.0f);
    vals[u] = s * fabsf(s) / (1.0f + s * s);
  }
  if (out) {
#pragma unroll
    for (int u = 0; u < 10; ++u) {
      int cc = c0 + u;
      int q = cc & 3, nb = cc >> 2;
      int bl = mwr * 16 + (lr >> 4) * 4 + q;
      int jo = nb * 16 + (lr & 15);
      out[(size_t)(bb * 32 + bl) * JO_ + jo] = vals[u];
    }
  }
  if (vfrag) {
    __syncthreads();  // all sm reads done before aliasing as vsm[32][162]
#pragma unroll
    for (int u = 0; u < 10; ++u) {
      int cc = c0 + u;
      int q = cc & 3, nb = cc >> 2;
      int bl = mwr * 16 + (lr >> 4) * 4 + q;
      int jo = nb * 16 + (lr & 15);
      sm[bl * 162 + jo] = vals[u];
    }
    __syncthreads();
    for (int ch = tid; ch < 640; ch += 512) {
      int nb = ch >> 6, l2 = ch & 63;
      bf16x8 pk;
#pragma unroll
      for (int t = 0; t < 8; ++t)
        pk[t] = f2bf(sm[((l2 >> 4) * 8 + t) * 162 + nb * 16 + (l2 & 15)]);
      ((bf16x8*)vfrag)[(size_t)(bb * 10 + nb) * 64 + l2] = pk;
    }
  }
}

// Agreement: per r-pair, M[16x160] = x_r^T @ v over K=B=512 (4 waves x 128),
// then bias[r,j] += (1/B) sum_{i,o} W * M, fused in-block. grid 576.
__global__ __launch_bounds__(256) void agree_kernel(
    const float* __restrict__ x, const short* __restrict__ xtf,
    const float* __restrict__ W, const short* __restrict__ vfrag,
    float* __restrict__ bias) {
  __shared__ float Msm[4][16][176];
  __shared__ float red[320];
  const int tid = threadIdx.x;
  const int w = tid >> 6, lane = tid & 63;
  const int rp = blockIdx.x;
  const int r0 = rp * 2;

  f32x4 acc[10] = {};
  if (xtf) {
    const bf16x8* ap = (const bf16x8*)xtf + ((size_t)rp * 16 + w * 4) * 64 + lane;
    const bf16x8* bp = (const bf16x8*)vfrag + ((size_t)(w * 4) * 640 + lane);
#pragma unroll
    for (int ks = 0; ks < 4; ++ks) {
      bf16x8 af = ap[0];
      ap += 64;
#pragma unroll
      for (int nb = 0; nb < 10; ++nb)
        acc[nb] = __builtin_amdgcn_mfma_f32_16x16x32_bf16(af, bp[nb * 64],
                                                          acc[nb], 0, 0, 0);
      bp += 640;
    }
  } else {
    const int rowa = lane & 15;
    const float* xp = x + (size_t)rp * 16 + rowa;
    for (int ks = 0; ks < 4; ++ks) {
      int b0 = w * 128 + ks * 32 + (lane >> 4) * 8;
      bf16x8 af;
#pragma unroll
      for (int t = 0; t < 8; ++t) af[t] = f2bf(xp[(size_t)(b0 + t) * K_]);
      const bf16x8* bp = (const bf16x8*)vfrag + ((w * 4 + ks) * 640 + lane);
#pragma unroll
      for (int nb = 0; nb < 10; ++nb)
        acc[nb] = __builtin_amdgcn_mfma_f32_16x16x32_bf16(af, bp[nb * 64],
                                                          acc[nb], 0, 0, 0);
    }
  }
  {
    int colc = lane & 15, rbase = (lane >> 4) * 4;
#pragma unroll
    for (int nb = 0; nb < 10; ++nb)
#pragma unroll
      for (int q = 0; q < 4; ++q)
        Msm[w][rbase + q][nb * 16 + colc] = acc[nb][q];
  }
  __syncthreads();
  for (int idx = tid; idx < 320; idx += 256) {
    int rr = idx / 160, jo = idx - rr * 160;
    int j = jo >> 4, o = jo & 15;
    float p = 0.0f;
    const float* wp = W + (((size_t)(r0 + rr) * 10 + j) * 16 + o) * 8;
#pragma unroll
    for (int i = 0; i < 8; ++i) {
      float m = Msm[0][rr * 8 + i][jo] + Msm[1][rr * 8 + i][jo] +
                Msm[2][rr * 8 + i][jo] + Msm[3][rr * 8 + i][jo];
      p += wp[i] * m;
    }
    red[idx] = p;
  }
  __syncthreads();
  if (tid < 20) {
    int rr = tid / 10, j = tid - rr * 10;
    float s = 0.0f;
#pragma unroll
    for (int o = 0; o < 16; ++o) s += red[rr * 160 + j * 16 + o];
    bias[(r0 + rr) * 10 + j] += s * (1.0f / 512.0f);
  }
}

// softmax over routes per j; fixed-order tree reductions (deterministic)
__global__ __launch_bounds__(256) void softmax_kernel(
    const float* __restrict__ bias, float* __restrict__ c) {
  __shared__ float red[256];
  const int j = blockIdx.x;
  const int tid = threadIdx.x;
  float m = -1e30f;
  for (int r = tid; r < R_; r += 256) m = fmaxf(m, bias[r * 10 + j]);
  red[tid] = m;
  __syncthreads();
  for (int s = 128; s > 0; s >>= 1) {
    if (tid < s) red[tid] = fmaxf(red[tid], red[tid + s]);
    __syncthreads();
  }
  m = red[0];
  __syncthreads();
  float sum = 0.0f;
  for (int r = tid; r < R_; r += 256) sum += expf(bias[r * 10 + j] - m);
  red[tid] = sum;
  __syncthreads();
  for (int s = 128; s > 0; s >>= 1) {
    if (tid < s) red[tid] += red[tid + s];
    __syncthreads();
  }
  float inv = 1.0f / red[0];
  for (int r = tid; r < R_; r += 256)
    c[r * 10 + j] = expf(bias[r * 10 + j] - m) * inv;
}

extern "C" void kernel_launch(void* const* d_in, const int* in_sizes, int n_in,
                              void* d_out, int out_size, void* d_ws,
                              size_t ws_size, hipStream_t stream) {
  const float* x = (const float*)d_in[0];  // [512,1152,8]
  const float* W = (const float*)d_in[1];  // [1152,10,16,8]
  float* out = (float*)d_out;              // [512][160]
  char* ws = (char*)d_ws;

  const size_t BASE = 3205120;  // bias|c|wcf|vfrag
  const size_t XAFB = 9437184, XTFB = 9437184;

  float* bias  = (float*)(ws);            // 11520 f
  float* c     = (float*)(ws + 46080);    // 11520 f
  short* wcf   = (short*)(ws + 92160);    // 184320 chunks * 16B
  short* vfrag = (short*)(ws + 3041280);  // 160 KB

  short* xaf = nullptr;
  short* xtf = nullptr;
  size_t cur = BASE;
  if (ws_size >= cur + XAFB) { xaf = (short*)(ws + cur); cur += XAFB; }
  if (ws_size >= cur + XTFB) { xtf = (short*)(ws + cur); cur += XTFB; }

  init_kernel<<<45, 256, 0, stream>>>(bias);
  if (xaf) xafbuild_kernel<<<2304, 256, 0, stream>>>(x, xaf);
  if (xtf) xtfbuild_kernel<<<2304, 256, 0, stream>>>(x, xtf);

  for (int it = 0; it < 3; ++it) {
    wcbuild_kernel<<<720, 256, 0, stream>>>(W, (it == 0) ? nullptr : c, wcf);
    short* vf = (it < 2) ? vfrag : nullptr;
    float* o = (it == 2) ? out : nullptr;
    if (it == 0)
      fwd_kernel<true><<<16, 512, 0, stream>>>(x, xaf, wcf, vf, o);
    else
      fwd_kernel<false><<<16, 512, 0, stream>>>(x, xaf, wcf, vf, o);
    if (it < 2) {
      agree_kernel<<<576, 256, 0, stream>>>(x, xtf, W, vfrag, bias);
      softmax_kernel<<<10, 256, 0, stream>>>(bias, c);
    }
  }
}

// Round 6
// 113.166 us; speedup vs baseline: 3.2469x; 3.2469x over previous
//
#include <hip/hip_runtime.h>

// DigitCaps routing via MFMA, u_hat never materialized.
// B=512, R=1152, J=10, O=16, I=8, JO=160, K=R*I=9216.
// s[b,jo]    = sum_k x[b,k] * Wc[k,jo],  Wc[(r,i),(j,o)] = W[r,j,o,i]*c[r,j]
// v          = s*|s|/(1+s^2)
// bias[r,j] += (1/B) sum_{i,o} W[r,j,o,i] * M[(r,i),(j,o)],  M = x_r^T @ v
// c          = softmax_r(bias)
//
// r5 lesson: fusing GEMM+reduce into 16 blocks collapsed occupancy (1.4%) and
// concentrated all wcf traffic on 16 CUs' L1s -> 107us. Keep 256-block GEMM.
// This round: wcbuild folded INTO sgemm (per-block LDS slice build with inline
// softmax from {m_j, invZ_j}); softmax kernel shrunk to a 20-float stat kernel;
// bias-zero folded into xafbuild. 12 dispatches total.

#define B_   512
#define R_   1152
#define JO_  160
#define K_   9216
#define KS_  32
#define SPK_ 9

typedef __attribute__((ext_vector_type(4))) float f32x4;
typedef __attribute__((ext_vector_type(8))) short bf16x8;

__device__ __forceinline__ short f2bf(float f) {
  unsigned int u = __float_as_uint(f);
  unsigned int r = (u + 0x7FFFu + ((u >> 16) & 1u)) >> 16;
  return (short)r;
}

// ---- one-time: x -> A-fragment order for the s-GEMM (+ zero bias).
// frag f = m16*288+ks; lane l: row m16*16+(l&15), k = ks*32+(l>>4)*8+t.
__global__ __launch_bounds__(256) void xafbuild_kernel(
    const float* __restrict__ x, short* __restrict__ xaf,
    float* __restrict__ bias) {
  int gid = blockIdx.x * 256 + threadIdx.x;  // < 589824
  if (gid < R_ * 10) bias[gid] = 0.0f;
  int lane = gid & 63, f = gid >> 6;
  int ks = f % 288, m16 = f / 288;
  int row = m16 * 16 + (lane & 15);
  int k0 = ks * 32 + (lane >> 4) * 8;
  const float4* p = (const float4*)(x + (size_t)row * K_ + k0);
  float4 a = p[0], b = p[1];
  bf16x8 pk;
  pk[0] = f2bf(a.x); pk[1] = f2bf(a.y); pk[2] = f2bf(a.z); pk[3] = f2bf(a.w);
  pk[4] = f2bf(b.x); pk[5] = f2bf(b.y); pk[6] = f2bf(b.z); pk[7] = f2bf(b.w);
  ((bf16x8*)xaf)[gid] = pk;
}

// ---- one-time: x^T -> A-fragment order for agreement.
// frag f = rp*16+kb; lane l: row (l&15) of r-pair rp, k = b = kb*32+(l>>4)*8+t.
__global__ __launch_bounds__(256) void xtfbuild_kernel(
    const float* __restrict__ x, short* __restrict__ xtf) {
  int gid = blockIdx.x * 256 + threadIdx.x;  // < 589824
  int lane = gid & 63, f = gid >> 6;
  int kb = f & 15, rp = f >> 4;
  int b0 = kb * 32 + (lane >> 4) * 8;
  const float* p = x + (size_t)b0 * K_ + rp * 16 + (lane & 15);
  bf16x8 pk;
#pragma unroll
  for (int t = 0; t < 8; ++t) pk[t] = f2bf(p[(size_t)t * K_]);
  ((bf16x8*)xtf)[gid] = pk;
}

// softmax stats over routes per j: mz[j] = max_r bias, mz[10+j] = 1/sum(exp).
// Fixed-order tree reductions (deterministic). grid 10.
__global__ __launch_bounds__(256) void stat_kernel(
    const float* __restrict__ bias, float* __restrict__ mz) {
  __shared__ float red[256];
  const int j = blockIdx.x;
  const int tid = threadIdx.x;
  float m = -1e30f;
  for (int r = tid; r < R_; r += 256) m = fmaxf(m, bias[r * 10 + j]);
  red[tid] = m;
  __syncthreads();
  for (int s = 128; s > 0; s >>= 1) {
    if (tid < s) red[tid] = fmaxf(red[tid], red[tid + s]);
    __syncthreads();
  }
  m = red[0];
  __syncthreads();
  float sum = 0.0f;
  for (int r = tid; r < R_; r += 256) sum += expf(bias[r * 10 + j] - m);
  red[tid] = sum;
  __syncthreads();
  for (int s = 128; s > 0; s >>= 1) {
    if (tid < s) red[tid] += red[tid + s];
    __syncthreads();
  }
  if (tid == 0) {
    mz[j] = m;
    mz[10 + j] = 1.0f / red[0];
  }
}

// s-GEMM with in-block Wc slice build.
// grid (8, 32): 4 waves = 4 m16-tiles; 9 k-steps per block.
// Build phase: 5760 16B fragments of W*c into LDS (92KB), c from bias+stats.
template <bool NEEDC>
__global__ __launch_bounds__(256) void sgemm_kernel(
    const short* __restrict__ xaf, const float* __restrict__ W,
    const float* __restrict__ bias, const float* __restrict__ mz,
    float* __restrict__ part) {
  __shared__ short wls[5760 * 8];  // 92160 B
  const int tid = threadIdx.x;
  const int w = tid >> 6, lane = tid & 63;
  const int ks0 = blockIdx.y * SPK_;
  bf16x8* wls8 = (bf16x8*)wls;

  for (int q = 0; q < 23; ++q) {
    int idx = q * 256 + tid;
    if (idx < 5760) {
      int l = idx & 63, sn = idx >> 6;     // sn < 90
      int nb = sn % 10, st = sn / 10;
      int r = (ks0 + st) * 4 + (l >> 4);
      int o = l & 15;
      const float4* wp =
          (const float4*)(W + (((size_t)r * 10 + nb) * 16 + o) * 8);
      float4 a = wp[0], b = wp[1];
      float cs = 1.0f;
      if (NEEDC) cs = expf(bias[r * 10 + nb] - mz[nb]) * mz[10 + nb];
      bf16x8 pk;
      pk[0] = f2bf(a.x * cs); pk[1] = f2bf(a.y * cs);
      pk[2] = f2bf(a.z * cs); pk[3] = f2bf(a.w * cs);
      pk[4] = f2bf(b.x * cs); pk[5] = f2bf(b.y * cs);
      pk[6] = f2bf(b.z * cs); pk[7] = f2bf(b.w * cs);
      wls8[idx] = pk;
    }
  }
  __syncthreads();

  const int m16 = blockIdx.x * 4 + w;
  f32x4 acc[10] = {};
  const bf16x8* ap = (const bf16x8*)xaf + ((size_t)m16 * 288 + ks0) * 64 + lane;
  const bf16x8* lp = wls8 + lane;
  for (int st = 0; st < SPK_; ++st) {
    bf16x8 af = ap[0];
    ap += 64;
#pragma unroll
    for (int nb = 0; nb < 10; ++nb)
      acc[nb] = __builtin_amdgcn_mfma_f32_16x16x32_bf16(af, lp[nb * 64],
                                                        acc[nb], 0, 0, 0);
    lp += 640;
  }
  // C/D: col=lane&15, row=(lane>>4)*4+q
  const float scale = NEEDC ? 1.0f : (1.0f / 1152.0f);
  float* pp = part + (size_t)blockIdx.y * (B_ * JO_) +
              (size_t)(m16 * 16 + (lane >> 4) * 4) * JO_ + (lane & 15);
#pragma unroll
  for (int nb = 0; nb < 10; ++nb)
#pragma unroll
    for (int q = 0; q < 4; ++q)
      pp[q * JO_ + nb * 16] = acc[nb][q] * scale;
}

// Reduce 32 k-splits + squash. grid 160 (one (kb,nb) 32x16 tile), block 512,
// 1 element/thread, explicit pv[32] so loads issue back-to-back.
__global__ __launch_bounds__(512) void squash_kernel(
    const float* __restrict__ part, short* __restrict__ vfrag,
    float* __restrict__ out) {
  __shared__ float vsm[32][17];
  const int tid = threadIdx.x;  // 0..511
  const int kb = blockIdx.x / 10, nb = blockIdx.x - (blockIdx.x / 10) * 10;
  const int bl = tid >> 4, col = tid & 15;
  const int b = kb * 32 + bl, jo = nb * 16 + col;
  const float* pe = part + (size_t)b * JO_ + jo;
  float pv[KS_];
#pragma unroll
  for (int ks = 0; ks < KS_; ++ks) pv[ks] = pe[(size_t)ks * (B_ * JO_)];
  float s = 0.0f;
#pragma unroll
  for (int ks = 0; ks < KS_; ++ks) s += pv[ks];
  float val = s * fabsf(s) / (1.0f + s * s);
  if (out) out[(size_t)b * JO_ + jo] = val;
  if (vfrag) {
    vsm[bl][col] = val;
    __syncthreads();
    if (tid < 64) {
      bf16x8 pk;
#pragma unroll
      for (int t = 0; t < 8; ++t)
        pk[t] = f2bf(vsm[(tid >> 4) * 8 + t][tid & 15]);
      ((bf16x8*)vfrag)[(size_t)blockIdx.x * 64 + tid] = pk;
    }
  }
}

// Agreement: per r-pair, M[16x160] = x_r^T @ v over K=B=512 (4 waves x 128),
// then bias[r,j] += (1/B) sum_{i,o} W * M, fused in-block. grid 576.
__global__ __launch_bounds__(256) void agree_kernel(
    const short* __restrict__ xtf, const float* __restrict__ W,
    const short* __restrict__ vfrag, float* __restrict__ bias) {
  __shared__ float Msm[4][16][176];
  __shared__ float red[320];
  const int tid = threadIdx.x;
  const int w = tid >> 6, lane = tid & 63;
  const int rp = blockIdx.x;
  const int r0 = rp * 2;

  f32x4 acc[10] = {};
  const bf16x8* ap = (const bf16x8*)xtf + ((size_t)rp * 16 + w * 4) * 64 + lane;
  const bf16x8* bp = (const bf16x8*)vfrag + ((size_t)(w * 4) * 640 + lane);
#pragma unroll
  for (int ks = 0; ks < 4; ++ks) {
    bf16x8 af = ap[0];
    ap += 64;
#pragma unroll
    for (int nb = 0; nb < 10; ++nb)
      acc[nb] = __builtin_amdgcn_mfma_f32_16x16x32_bf16(af, bp[nb * 64],
                                                        acc[nb], 0, 0, 0);
    bp += 640;
  }
  {
    int colc = lane & 15, rbase = (lane >> 4) * 4;
#pragma unroll
    for (int nb = 0; nb < 10; ++nb)
#pragma unroll
      for (int q = 0; q < 4; ++q)
        Msm[w][rbase + q][nb * 16 + colc] = acc[nb][q];
  }
  __syncthreads();
  for (int idx = tid; idx < 320; idx += 256) {
    int rr = idx / 160, jo = idx - rr * 160;
    int j = jo >> 4, o = jo & 15;
    float p = 0.0f;
    const float* wp = W + (((size_t)(r0 + rr) * 10 + j) * 16 + o) * 8;
#pragma unroll
    for (int i = 0; i < 8; ++i) {
      float m = Msm[0][rr * 8 + i][jo] + Msm[1][rr * 8 + i][jo] +
                Msm[2][rr * 8 + i][jo] + Msm[3][rr * 8 + i][jo];
      p += wp[i] * m;
    }
    red[idx] = p;
  }
  __syncthreads();
  if (tid < 20) {
    int rr = tid / 10, j = tid - rr * 10;
    float s = 0.0f;
#pragma unroll
    for (int o = 0; o < 16; ++o) s += red[rr * 160 + j * 16 + o];
    bias[(r0 + rr) * 10 + j] += s * (1.0f / 512.0f);
  }
}

extern "C" void kernel_launch(void* const* d_in, const int* in_sizes, int n_in,
                              void* d_out, int out_size, void* d_ws,
                              size_t ws_size, hipStream_t stream) {
  const float* x = (const float*)d_in[0];  // [512,1152,8]
  const float* W = (const float*)d_in[1];  // [1152,10,16,8]
  float* out = (float*)d_out;              // [512][160]
  char* ws = (char*)d_ws;

  // layout (bytes): bias@0 (46080) | mz@46080 (80) | vfrag@46160 (163840)
  //                 xaf@210000 (9437184) | xtf@9647184 (9437184) | part@19084368
  float* bias  = (float*)(ws);
  float* mz    = (float*)(ws + 46080);
  short* vfrag = (short*)(ws + 46160);
  short* xaf   = (short*)(ws + 210000);
  short* xtf   = (short*)(ws + 9647184);
  float* part  = (float*)(ws + 19084368);  // 32 * 512*160 f = 10.5 MB

  xafbuild_kernel<<<2304, 256, 0, stream>>>(x, xaf, bias);
  xtfbuild_kernel<<<2304, 256, 0, stream>>>(x, xtf);

  // iter 0: uniform c = 1/1152 folded into epilogue scale
  sgemm_kernel<false><<<dim3(8, KS_), 256, 0, stream>>>(xaf, W, nullptr,
                                                        nullptr, part);
  squash_kernel<<<160, 512, 0, stream>>>(part, vfrag, nullptr);
  agree_kernel<<<576, 256, 0, stream>>>(xtf, W, vfrag, bias);
  // iter 1
  stat_kernel<<<10, 256, 0, stream>>>(bias, mz);
  sgemm_kernel<true><<<dim3(8, KS_), 256, 0, stream>>>(xaf, W, bias, mz, part);
  squash_kernel<<<160, 512, 0, stream>>>(part, vfrag, nullptr);
  agree_kernel<<<576, 256, 0, stream>>>(xtf, W, vfrag, bias);
  // iter 2
  stat_kernel<<<10, 256, 0, stream>>>(bias, mz);
  sgemm_kernel<true><<<dim3(8, KS_), 256, 0, stream>>>(xaf, W, bias, mz, part);
  squash_kernel<<<160, 512, 0, stream>>>(part, nullptr, out);
}